// Round 14
// baseline (5530.355 us; speedup 1.0000x reference)
//
#include <hip/hip_runtime.h>

// ---------------- problem constants ----------------
#define T_TOKENS 8192
#define H_DIM    2048
#define I_DIM    4096
#define NE       8
#define NPAIR    16384                  // T_TOKENS * TOP_K
#define PADBM    256                    // expert segment padding (= BM of GEMM tiles)
#define PADP     (NPAIR + NE * PADBM)   // 18432 worst-case padded rows
#define RT_MAX   (PADP / PADBM)         // 72 max row tiles (72 = 9*8, XCD-exact)

// 256x256 tile geometry; K-step 32 (2 phases/K-tile), 2 blocks/CU
#define BM2 256
#define BN2 256
#define NTHR 512
#define NKT_UP (H_DIM / 64)             // 32 (64-wide producer tiles)
#define NKT_DN (I_DIM / 64)             // 64
#define NKT32_UP (H_DIM / 32)           // 64 GEMM K-steps
#define NKT32_DN (I_DIM / 32)           // 128
#define NTN_UP (I_DIM / BN2)            // 16
#define NTN_DN (H_DIM / BN2)            // 8
#define TILE_B 32768                    // bytes per 256x64 bf16 producer tile
#define TILE_S 16384                    // shorts per producer tile
#define TILE32_B 16384                  // bytes per 256x32 GEMM operand tile

#define G_UP    (RT_MAX * NTN_UP)       // 1152 up tiles
#define G_CVTD  (NE * NTN_DN * NKT_DN)  // 4096 cvt-down tiles
#define G_DN    (RT_MAX * NTN_DN)       // 576 down tiles
#define G_GATH  (RT_MAX * NKT_UP)       // 2304 gather tiles
#define G_CVTU  (NE * NTN_UP * NKT_UP)  // 4096 cvt-up tiles

// ---------------- workspace sizes (bytes) ----------------
#define AB_BYTES  ((size_t)RT_MAX * NKT_UP * TILE_B)   // 75.5 MB (Yb overlaps)
#define W_BYTES   ((size_t)NE * I_DIM * H_DIM * 2)     // 134.2 MB
#define HB_BYTES  ((size_t)RT_MAX * NKT_DN * TILE_B)   // 151.0 MB
#define TOK_BYTES ((size_t)PADP * 4)

typedef __attribute__((ext_vector_type(8))) short bf16x8;   // 8 bf16 = 4 VGPRs
typedef __attribute__((ext_vector_type(4))) float f32x4;    // MFMA C/D

__device__ __forceinline__ unsigned short f2bf(float f) {
  union { float f; unsigned u; } a; a.f = f;
  unsigned r = a.u + 0x7fffu + ((a.u >> 16) & 1u);   // RNE
  return (unsigned short)(r >> 16);
}

__device__ __forceinline__ float b2f(unsigned short b) {
  union { unsigned u; float f; } a; a.u = ((unsigned)b) << 16;
  return a.f;
}

__device__ __forceinline__ bf16x8 pack8(float4 a, float4 b) {
  bf16x8 o;
  o[0] = (short)f2bf(a.x); o[1] = (short)f2bf(a.y);
  o[2] = (short)f2bf(a.z); o[3] = (short)f2bf(a.w);
  o[4] = (short)f2bf(b.x); o[5] = (short)f2bf(b.y);
  o[6] = (short)f2bf(b.z); o[7] = (short)f2bf(b.w);
  return o;
}

__device__ __forceinline__ void gload16(const void* g, void* l) {
  __builtin_amdgcn_global_load_lds(
      (const __attribute__((address_space(1))) unsigned int*)g,
      (__attribute__((address_space(3))) unsigned int*)l,
      16, 0, 0);
}

// LDS bank-spread involution for [c][r][16B] tiles: XOR bits 5:6 with bits 7:8.
__device__ __forceinline__ int swz(int a) { return a ^ ((a >> 2) & 0x60); }

__device__ __forceinline__ int expert_of(int row0, const int* pstart) {
  int e = 0;
  #pragma unroll
  for (int q = 1; q < NE; ++q) if (row0 >= pstart[q]) e = q;
  return e;
}

// 2D XCD-locality decode: XCD(bid%8) = (rt%4)*2 + (nt%2). Bijective.
__device__ __forceinline__ void rt_nt_decode(int bid, int NTN, int& rt, int& nt) {
  int xcd = bid & 7, g = bid >> 3;
  int gh = NTN >> 1;
  int gn = g % gh, gr = g / gh;
  rt = gr * 4 + (xcd >> 1);
  nt = gn * 2 + (xcd & 1);
}

// ---------------- routing: single-block count/scan/scatter + tok init ----------------
__global__ __launch_bounds__(512) void route_all(const int* __restrict__ idx,
                                                 int* __restrict__ meta,
                                                 int* __restrict__ tok) {
  __shared__ int cnt[NE], base[NE + 1], cur[NE];
  int t = threadIdx.x;
  if (t < NE) { cnt[t] = 0; cur[t] = 0; }
  for (int i = t; i < PADP; i += 512) tok[i] = -1;   // -1 = padding
  __syncthreads();
  for (int i = t; i < NPAIR; i += 512) atomicAdd(&cnt[idx[i]], 1);
  __syncthreads();
  if (t == 0) {
    int off = 0;
    for (int e = 0; e < NE; ++e) {
      base[e] = off;
      off += ((cnt[e] + PADBM - 1) / PADBM) * PADBM;
    }
    base[NE] = off;
    for (int e = 0; e <= NE; ++e) meta[16 + e] = base[e];
  }
  __syncthreads();
  for (int i = t; i < NPAIR; i += 512) {
    int e = idx[i];
    int pos = base[e] + atomicAdd(&cur[e], 1);
    tok[pos] = i;                       // pair index; token = i>>1 (TOP_K=2)
  }
}

// ---------------- weight fp32 -> tiled bf16 tile body (LDS-staged transpose) ----------------
__device__ __forceinline__ void cvt_tile_body(
    const float* __restrict__ W, unsigned short* __restrict__ out,
    int tile, int NKT, int K, char* lt) {
  int kt = tile % NKT, panel = tile / NKT;
  int t = threadIdx.x, r = t >> 1, half = t & 1;
  const float* src = W + ((size_t)panel * 256 + r) * K + kt * 64 + half * 32;
  float4 v[8];
  #pragma unroll
  for (int i = 0; i < 8; ++i) v[i] = ((const float4*)src)[i];
  #pragma unroll
  for (int i2 = 0; i2 < 4; ++i2) {
    int c = half * 4 + i2;
    *(bf16x8*)(lt + swz(c * 4096 + r * 16)) = pack8(v[2 * i2], v[2 * i2 + 1]);
  }
  __syncthreads();
  char* dst = (char*)(out + (size_t)tile * TILE_S);
  int tb = t * 16;
  #pragma unroll
  for (int i = 0; i < 4; ++i) {
    int o = i * 8192 + tb;
    *(bf16x8*)(dst + o) = *(const bf16x8*)(lt + swz(o));
  }
}

// ---------------- gathered x fp32 -> tiled bf16 A tile body (LDS-staged) ----------------
__device__ __forceinline__ void gather_tile_body(
    const float* __restrict__ x, const int* __restrict__ tok,
    unsigned short* __restrict__ out, int bid, char* lt) {
  int kt = bid & (NKT_UP - 1), rt = bid >> 5;
  int t = threadIdx.x, r = t >> 1, half = t & 1;
  int v = tok[rt * 256 + r];
  bf16x8 pk[4];
  if (v < 0) {
    #pragma unroll
    for (int i2 = 0; i2 < 4; ++i2) pk[i2] = (bf16x8)0;
  } else {
    const float* src = x + (size_t)(v >> 1) * H_DIM + kt * 64 + half * 32;
    float4 w[8];
    #pragma unroll
    for (int i = 0; i < 8; ++i) w[i] = ((const float4*)src)[i];
    #pragma unroll
    for (int i2 = 0; i2 < 4; ++i2) pk[i2] = pack8(w[2 * i2], w[2 * i2 + 1]);
  }
  #pragma unroll
  for (int i2 = 0; i2 < 4; ++i2) {
    int c = half * 4 + i2;
    *(bf16x8*)(lt + swz(c * 4096 + r * 16)) = pk[i2];
  }
  __syncthreads();
  char* dst = (char*)(out + (size_t)bid * TILE_S);   // [rt][kt] order
  int tb = t * 16;
  #pragma unroll
  for (int i = 0; i < 4; ++i) {
    int o = i * 8192 + tb;
    *(bf16x8*)(dst + o) = *(const bf16x8*)(lt + swz(o));
  }
}

// ---------------- fused producers: gather-A tiles + cvt-up tiles (independent) ----------------
__global__ __launch_bounds__(512) void gather_cvt_up(
    const float* __restrict__ x, const int* __restrict__ tok,
    unsigned short* __restrict__ ab,
    const float* __restrict__ upW, unsigned short* __restrict__ wtU) {
  __shared__ float4 ltq[TILE_B / 16];
  int b = blockIdx.x;
  if (b < G_GATH) gather_tile_body(x, tok, ab, b, (char*)ltq);
  else            cvt_tile_body(upW, wtU, b - G_GATH, NKT_UP, H_DIM, (char*)ltq);
}

// standalone cvt (fallback path for down-weights)
__global__ __launch_bounds__(512) void cvt_tile_w(
    const float* __restrict__ W, unsigned short* __restrict__ out,
    int NKT, int K) {
  __shared__ float4 ltq[TILE_B / 16];
  cvt_tile_body(W, out, blockIdx.x, NKT, K, (char*)ltq);
}

// ---------------- BK=32 2-phase grouped-GEMM core, 2 blocks/CU ----------------
// LDS (64KB dynamic): A dbuf [2][16KB] at 0; B dbuf [2][16KB] at 32768.
// Producer tiles are 64-wide [8c][256r][16B]; a 32-wide GEMM tile (4 kc-chunks)
// is a contiguous 16KB half of it -> t32*TILE32_B indexing is layout-exact.
// Per K-tile: fh0 {ds_read A-lo + B; stage A,B of t+1 (4 loads); MFMA acc[0..3]},
// fh1 {ds_read A-hi; vmcnt(0); MFMA acc[4..7]}. Prefetch distance is 1 phase;
// the co-resident second block covers the exposed latency (TLP).

#define STAGE32(KT, BS) do {                                                   \
    const char* aT_ = aTile + (size_t)(KT) * TILE32_B;                         \
    const char* bT_ = bTile + (size_t)(KT) * TILE32_B;                         \
    _Pragma("unroll")                                                          \
    for (int l_ = 0; l_ < 2; ++l_) {                                           \
      int off_ = (l_ * 8 + wv) * 1024 + lane16;                                \
      gload16(aT_ + off_, smem + (BS) * 16384 + off_);                         \
      gload16(bT_ + off_, smem + 32768 + (BS) * 16384 + off_);                 \
    }                                                                          \
  } while (0)

#define PHASE32(FH, DO_STAGE, DO_VM) do {                                      \
    bf16x8 af[4];                                                              \
    const char* aB_ = smem + bufc * 16384 + hi * 4096;                         \
    _Pragma("unroll")                                                          \
    for (int f = 0; f < 4; ++f)                                                \
      af[f] = *(const bf16x8*)(aB_ + arow_b + ((FH) * 4 + f) * 256);           \
    if ((FH) == 0) {                                                           \
      const char* bB_ = smem + 32768 + bufc * 16384 + hi * 4096;               \
      _Pragma("unroll")                                                        \
      for (int f = 0; f < 4; ++f)                                              \
        bfr[f] = *(const bf16x8*)(bB_ + brow_b + f * 256);                     \
    }                                                                          \
    DO_STAGE;                                                                  \
    DO_VM;                                                                     \
    __builtin_amdgcn_s_barrier();                                              \
    asm volatile("s_waitcnt lgkmcnt(0)" ::: "memory");                         \
    __builtin_amdgcn_s_setprio(1);                                             \
    _Pragma("unroll")                                                          \
    for (int fm = 0; fm < 4; ++fm)                                             \
      _Pragma("unroll")                                                        \
      for (int fn = 0; fn < 4; ++fn)                                           \
        acc[(FH) * 4 + fm][fn] = __builtin_amdgcn_mfma_f32_16x16x32_bf16(      \
            af[fm], bfr[fn], acc[(FH) * 4 + fm][fn], 0, 0, 0);                 \
    __builtin_amdgcn_s_setprio(0);                                             \
    __builtin_amdgcn_s_barrier();                                              \
  } while (0)

#define GEMM32_PROLOGUE()                                                      \
  STAGE32(0, 0);                                                               \
  asm volatile("s_waitcnt vmcnt(0)" ::: "memory");                             \
  __builtin_amdgcn_s_barrier();

#define GEMM32_MAIN(NKT32)                                                     \
  int bufc = 0;                                                                \
  for (int kt = 0; kt < (NKT32); ++kt) {                                       \
    int ktn = (kt + 1 < (NKT32)) ? kt + 1 : (NKT32) - 1;                       \
    PHASE32(0, STAGE32(ktn, bufc ^ 1), (void)0);                               \
    PHASE32(1, (void)0,                                                        \
            asm volatile("s_waitcnt vmcnt(0)" ::: "memory"));                  \
    bufc ^= 1;                                                                 \
  }

// ---------------- up-tile body: Hb[rt] tile = relu2(A @ up^T), tiled write ----------------
__device__ __forceinline__ void up_tile_body(
    int rt, int nt, int e,
    const unsigned short* __restrict__ Ab, const unsigned short* __restrict__ WtU,
    unsigned short* __restrict__ Hb, char* smem) {
  int tid = threadIdx.x;
  int wv = tid >> 6, lane = tid & 63;
  int lane16 = lane * 16;
  const char* aTile = (const char*)Ab + (size_t)rt * NKT_UP * TILE_B;
  const char* bTile = (const char*)WtU + (size_t)(e * NTN_UP + nt) * NKT_UP * TILE_B;
  int wm = wv >> 2, wn = wv & 3;
  int hi = lane >> 4;
  int arow_b = (wm * 128 + (lane & 15)) * 16;
  int brow_b = (wn * 64 + (lane & 15)) * 16;
  f32x4 acc[8][4] = {};
  bf16x8 bfr[4];
  GEMM32_PROLOGUE();
  GEMM32_MAIN(NKT32_UP);
  unsigned short* baseT = Hb + ((size_t)rt * NKT_DN + nt * 4 + wn) * TILE_S
                             + ((lane & 15) >> 3) * 2048 + (lane & 7);
  #pragma unroll
  for (int fm = 0; fm < 8; ++fm) {
    #pragma unroll
    for (int j = 0; j < 4; ++j) {
      int r = wm * 128 + hi * 4 + fm * 16 + j;
      unsigned short* rb = baseT + r * 8;
      #pragma unroll
      for (int fn = 0; fn < 4; ++fn) {
        float v = acc[fm][fn][j];
        v = v > 0.f ? v * v : 0.f;
        rb[fn * 4096] = f2bf(v);
      }
    }
  }
}

// ---------------- down-tile body: Yb[pair] cols = Hb[rt] @ down^T ----------------
__device__ __forceinline__ void down_tile_body(
    int rt, int nt, int e,
    const unsigned short* __restrict__ Hb, const unsigned short* __restrict__ WtD,
    unsigned short* __restrict__ Yb, const int* __restrict__ tok, char* smem) {
  int tid = threadIdx.x;
  int wv = tid >> 6, lane = tid & 63;
  int lane16 = lane * 16;
  const char* aTile = (const char*)Hb + (size_t)rt * NKT_DN * TILE_B;
  const char* bTile = (const char*)WtD + (size_t)(e * NTN_DN + nt) * NKT_DN * TILE_B;
  int wm = wv >> 2, wn = wv & 3;
  int hi = lane >> 4;
  int arow_b = (wm * 128 + (lane & 15)) * 16;
  int brow_b = (wn * 64 + (lane & 15)) * 16;
  f32x4 acc[8][4] = {};
  bf16x8 bfr[4];
  GEMM32_PROLOGUE();
  GEMM32_MAIN(NKT32_DN);
  int row0 = rt * BM2;
  int crow0 = row0 + wm * 128 + hi * 4;
  int ccol0 = nt * BN2 + wn * 64 + (lane & 15);
  #pragma unroll
  for (int fm = 0; fm < 8; ++fm) {
    #pragma unroll
    for (int j = 0; j < 4; ++j) {
      int p = crow0 + fm * 16 + j;
      int i = tok[p];
      if (i < 0) continue;
      unsigned short* dst = Yb + (size_t)i * H_DIM + ccol0;
      #pragma unroll
      for (int fn = 0; fn < 4; ++fn)
        dst[fn * 16] = f2bf(acc[fm][fn][j]);
    }
  }
}

// ---------------- FUSED GEMM1 + cvt_dn: blocks >= nGemm convert down-weights ----------------
__global__ __launch_bounds__(NTHR, 4) void gemm_up8f(
    const unsigned short* __restrict__ Ab, const unsigned short* __restrict__ WtU,
    unsigned short* __restrict__ Hb, const int* __restrict__ meta,
    const float* __restrict__ dnW, unsigned short* __restrict__ WtD,
    int nGemm) {
  extern __shared__ char smem[];
  if ((int)blockIdx.x >= nGemm) {
    cvt_tile_body(dnW, WtD, (int)blockIdx.x - nGemm, NKT_DN, I_DIM, smem);
    return;
  }
  const int* pstart = meta + 16;
  int rt, nt;
  rt_nt_decode(blockIdx.x, NTN_UP, rt, nt);
  if (rt * BM2 >= pstart[NE]) return;
  int e = expert_of(rt * BM2, pstart);
  up_tile_body(rt, nt, e, Ab, WtU, Hb, smem);
}

// ---------------- GEMM2: ybuf[pair] = h @ down_tiled^T ----------------
__global__ __launch_bounds__(NTHR, 4) void gemm_down8(
    const unsigned short* __restrict__ Hb, const unsigned short* __restrict__ Wt,
    unsigned short* __restrict__ Yb, const int* __restrict__ meta,
    const int* __restrict__ tok) {
  extern __shared__ char smem[];
  const int* pstart = meta + 16;
  int rt, nt;
  rt_nt_decode(blockIdx.x, NTN_DN, rt, nt);
  if (rt * BM2 >= pstart[NE]) return;
  int e = expert_of(rt * BM2, pstart);
  down_tile_body(rt, nt, e, Hb, Wt, Yb, tok, smem);
}

// ---------------- combine: out[t] = w0*y[2t] + w1*y[2t+1] (4 tokens/block) ----------------
__global__ __launch_bounds__(256) void combine(
    const unsigned short* __restrict__ Yb, const float* __restrict__ tkw,
    float* __restrict__ out) {
  int h0 = threadIdx.x * 8;
  #pragma unroll
  for (int tt = 0; tt < 4; ++tt) {
    int t = blockIdx.x * 4 + tt;
    float w0 = tkw[2 * t], w1 = tkw[2 * t + 1];
    bf16x8 ya = *(const bf16x8*)(Yb + (size_t)(2 * t) * H_DIM + h0);
    bf16x8 yb = *(const bf16x8*)(Yb + (size_t)(2 * t + 1) * H_DIM + h0);
    float* dst = out + (size_t)t * H_DIM + h0;
    float4 o0, o1;
    o0.x = w0 * b2f((unsigned short)ya[0]) + w1 * b2f((unsigned short)yb[0]);
    o0.y = w0 * b2f((unsigned short)ya[1]) + w1 * b2f((unsigned short)yb[1]);
    o0.z = w0 * b2f((unsigned short)ya[2]) + w1 * b2f((unsigned short)yb[2]);
    o0.w = w0 * b2f((unsigned short)ya[3]) + w1 * b2f((unsigned short)yb[3]);
    o1.x = w0 * b2f((unsigned short)ya[4]) + w1 * b2f((unsigned short)yb[4]);
    o1.y = w0 * b2f((unsigned short)ya[5]) + w1 * b2f((unsigned short)yb[5]);
    o1.z = w0 * b2f((unsigned short)ya[6]) + w1 * b2f((unsigned short)yb[6]);
    o1.w = w0 * b2f((unsigned short)ya[7]) + w1 * b2f((unsigned short)yb[7]);
    ((float4*)dst)[0] = o0;
    ((float4*)dst)[1] = o1;
  }
}

// ---------------- launch ----------------
extern "C" void kernel_launch(void* const* d_in, const int* in_sizes, int n_in,
                              void* d_out, int out_size, void* d_ws, size_t ws_size,
                              hipStream_t stream) {
  const float* x   = (const float*)d_in[0];
  const int*   tki = (const int*)d_in[1];
  const float* tkw = (const float*)d_in[2];
  const float* up  = (const float*)d_in[3];
  const float* dn  = (const float*)d_in[4];
  float* out = (float*)d_out;
  char* ws = (char*)d_ws;

  // Fused layout: AB | WtU | WtD | Hb | tok | meta   (~495 MB)
  // Serial layout: AB | Wt(shared) | Hb | tok | meta (~361 MB) — WtD == WtU.
  size_t need_fused = AB_BYTES + 2 * W_BYTES + HB_BYTES + TOK_BYTES + 4096;
  bool fused = ws_size >= need_fused;

  char* p = ws;
  unsigned short* ab  = (unsigned short*)p; p += AB_BYTES;
  unsigned short* wtU = (unsigned short*)p; p += W_BYTES;
  unsigned short* wtD = fused ? (unsigned short*)p : wtU;
  if (fused) p += W_BYTES;
  unsigned short* hb  = (unsigned short*)p; p += HB_BYTES;
  int* tok  = (int*)p; p += TOK_BYTES;
  int* meta = (int*)p;
  unsigned short* yb = ab;              // Yb overlaps dead Ab

  hipFuncSetAttribute((const void*)gemm_up8f,
                      hipFuncAttributeMaxDynamicSharedMemorySize, 65536);
  hipFuncSetAttribute((const void*)gemm_down8,
                      hipFuncAttributeMaxDynamicSharedMemorySize, 65536);

  route_all<<<1, 512, 0, stream>>>(tki, meta, tok);

  // fused independent producers: gather-A + cvt-up (one launch, one tail)
  gather_cvt_up<<<G_GATH + G_CVTU, 512, 0, stream>>>(x, tok, ab, up, wtU);

  if (fused) {
    // gemm_up blocks first (start immediately); cvt_dn blocks fill the tail.
    gemm_up8f<<<G_UP + G_CVTD, NTHR, 65536, stream>>>(ab, wtU, hb, meta,
                                                      dn, wtD, G_UP);
  } else {
    gemm_up8f<<<G_UP, NTHR, 65536, stream>>>(ab, wtU, hb, meta, dn, wtD, G_UP);
    cvt_tile_w<<<G_CVTD, 512, 0, stream>>>(dn, wtD, NKT_DN, I_DIM);
  }

  gemm_down8<<<G_DN, NTHR, 65536, stream>>>(hb, wtD, yb, meta, tok);

  combine<<<T_TOKENS / 4, 256, 0, stream>>>(yb, tkw, out);
}

// Round 15
// 809.725 us; speedup vs baseline: 6.8299x; 6.8299x over previous
//
#include <hip/hip_runtime.h>

// ---------------- problem constants ----------------
#define T_TOKENS 8192
#define H_DIM    2048
#define I_DIM    4096
#define NE       8
#define NPAIR    16384                  // T_TOKENS * TOP_K
#define PADBM    256                    // expert segment padding (= BM of GEMM tiles)
#define PADP     (NPAIR + NE * PADBM)   // 18432 worst-case padded rows
#define RT_MAX   (PADP / PADBM)         // 72 max row tiles (72 = 9*8, XCD-exact)

// 256x256x64 8-phase GEMM geometry
#define BM2 256
#define BN2 256
#define BK2 64
#define NTHR 512
#define NKT_UP (H_DIM / BK2)            // 32
#define NKT_DN (I_DIM / BK2)            // 64
#define NTN_UP (I_DIM / BN2)            // 16
#define NTN_DN (H_DIM / BN2)            // 8
#define TILE_B 32768                    // bytes per 256x64 bf16 operand tile
#define TILE_S 16384                    // shorts per tile

#define G_UP    (RT_MAX * NTN_UP)       // 1152 up tiles
#define G_CVTD  (NE * NTN_DN * NKT_DN)  // 4096 cvt-down tiles
#define G_DN    (RT_MAX * NTN_DN)       // 576 down tiles
#define G_GATH  (RT_MAX * NKT_UP)       // 2304 gather tiles
#define G_CVTU  (NE * NTN_UP * NKT_UP)  // 4096 cvt-up tiles

// ---------------- workspace sizes (bytes) ----------------
#define AB_BYTES  ((size_t)RT_MAX * NKT_UP * TILE_B)   // 75.5 MB (Yb overlaps)
#define W_BYTES   ((size_t)NE * I_DIM * H_DIM * 2)     // 134.2 MB
#define HB_BYTES  ((size_t)RT_MAX * NKT_DN * TILE_B)   // 151.0 MB
#define TOK_BYTES ((size_t)PADP * 4)

typedef __attribute__((ext_vector_type(8))) short bf16x8;   // 8 bf16 = 4 VGPRs
typedef __attribute__((ext_vector_type(4))) float f32x4;    // MFMA C/D

__device__ __forceinline__ unsigned short f2bf(float f) {
  union { float f; unsigned u; } a; a.f = f;
  unsigned r = a.u + 0x7fffu + ((a.u >> 16) & 1u);   // RNE
  return (unsigned short)(r >> 16);
}

__device__ __forceinline__ float b2f(unsigned short b) {
  union { unsigned u; float f; } a; a.u = ((unsigned)b) << 16;
  return a.f;
}

__device__ __forceinline__ bf16x8 pack8(float4 a, float4 b) {
  bf16x8 o;
  o[0] = (short)f2bf(a.x); o[1] = (short)f2bf(a.y);
  o[2] = (short)f2bf(a.z); o[3] = (short)f2bf(a.w);
  o[4] = (short)f2bf(b.x); o[5] = (short)f2bf(b.y);
  o[6] = (short)f2bf(b.z); o[7] = (short)f2bf(b.w);
  return o;
}

__device__ __forceinline__ void gload16(const void* g, void* l) {
  __builtin_amdgcn_global_load_lds(
      (const __attribute__((address_space(1))) unsigned int*)g,
      (__attribute__((address_space(3))) unsigned int*)l,
      16, 0, 0);
}

// LDS bank-spread involution for [c][r][16B] tiles: XOR bits 5:6 with bits 7:8.
__device__ __forceinline__ int swz(int a) { return a ^ ((a >> 2) & 0x60); }

__device__ __forceinline__ int expert_of(int row0, const int* pstart) {
  int e = 0;
  #pragma unroll
  for (int q = 1; q < NE; ++q) if (row0 >= pstart[q]) e = q;
  return e;
}

// 2D XCD-locality decode: XCD(bid%8) = (rt%4)*2 + (nt%2). Bijective.
__device__ __forceinline__ void rt_nt_decode(int bid, int NTN, int& rt, int& nt) {
  int xcd = bid & 7, g = bid >> 3;
  int gh = NTN >> 1;
  int gn = g % gh, gr = g / gh;
  rt = gr * 4 + (xcd >> 1);
  nt = gn * 2 + (xcd & 1);
}

// ---------------- routing: single-block count/scan/scatter + tok init ----------------
__global__ __launch_bounds__(512) void route_all(const int* __restrict__ idx,
                                                 int* __restrict__ meta,
                                                 int* __restrict__ tok) {
  __shared__ int cnt[NE], base[NE + 1], cur[NE];
  int t = threadIdx.x;
  if (t < NE) { cnt[t] = 0; cur[t] = 0; }
  for (int i = t; i < PADP; i += 512) tok[i] = -1;   // -1 = padding
  __syncthreads();
  for (int i = t; i < NPAIR; i += 512) atomicAdd(&cnt[idx[i]], 1);
  __syncthreads();
  if (t == 0) {
    int off = 0;
    for (int e = 0; e < NE; ++e) {
      base[e] = off;
      off += ((cnt[e] + PADBM - 1) / PADBM) * PADBM;
    }
    base[NE] = off;
    for (int e = 0; e <= NE; ++e) meta[16 + e] = base[e];
  }
  __syncthreads();
  for (int i = t; i < NPAIR; i += 512) {
    int e = idx[i];
    int pos = base[e] + atomicAdd(&cur[e], 1);
    tok[pos] = i;                       // pair index; token = i>>1 (TOP_K=2)
  }
}

// ---------------- weight fp32 -> tiled bf16 tile body (LDS-staged transpose) ----------------
__device__ __forceinline__ void cvt_tile_body(
    const float* __restrict__ W, unsigned short* __restrict__ out,
    int tile, int NKT, int K, char* lt) {
  int kt = tile % NKT, panel = tile / NKT;
  int t = threadIdx.x, r = t >> 1, half = t & 1;
  const float* src = W + ((size_t)panel * 256 + r) * K + kt * 64 + half * 32;
  float4 v[8];
  #pragma unroll
  for (int i = 0; i < 8; ++i) v[i] = ((const float4*)src)[i];
  #pragma unroll
  for (int i2 = 0; i2 < 4; ++i2) {
    int c = half * 4 + i2;
    *(bf16x8*)(lt + swz(c * 4096 + r * 16)) = pack8(v[2 * i2], v[2 * i2 + 1]);
  }
  __syncthreads();
  char* dst = (char*)(out + (size_t)tile * TILE_S);
  int tb = t * 16;
  #pragma unroll
  for (int i = 0; i < 4; ++i) {
    int o = i * 8192 + tb;
    *(bf16x8*)(dst + o) = *(const bf16x8*)(lt + swz(o));
  }
}

// ---------------- gathered x fp32 -> tiled bf16 A tile body (LDS-staged) ----------------
__device__ __forceinline__ void gather_tile_body(
    const float* __restrict__ x, const int* __restrict__ tok,
    unsigned short* __restrict__ out, int bid, char* lt) {
  int kt = bid & (NKT_UP - 1), rt = bid >> 5;
  int t = threadIdx.x, r = t >> 1, half = t & 1;
  int v = tok[rt * 256 + r];
  bf16x8 pk[4];
  if (v < 0) {
    #pragma unroll
    for (int i2 = 0; i2 < 4; ++i2) pk[i2] = (bf16x8)0;
  } else {
    const float* src = x + (size_t)(v >> 1) * H_DIM + kt * 64 + half * 32;
    float4 w[8];
    #pragma unroll
    for (int i = 0; i < 8; ++i) w[i] = ((const float4*)src)[i];
    #pragma unroll
    for (int i2 = 0; i2 < 4; ++i2) pk[i2] = pack8(w[2 * i2], w[2 * i2 + 1]);
  }
  #pragma unroll
  for (int i2 = 0; i2 < 4; ++i2) {
    int c = half * 4 + i2;
    *(bf16x8*)(lt + swz(c * 4096 + r * 16)) = pk[i2];
  }
  __syncthreads();
  char* dst = (char*)(out + (size_t)bid * TILE_S);   // [rt][kt] order
  int tb = t * 16;
  #pragma unroll
  for (int i = 0; i < 4; ++i) {
    int o = i * 8192 + tb;
    *(bf16x8*)(dst + o) = *(const bf16x8*)(lt + swz(o));
  }
}

// ---------------- fused producers: gather-A tiles + cvt-up tiles (independent) ----------------
__global__ __launch_bounds__(512) void gather_cvt_up(
    const float* __restrict__ x, const int* __restrict__ tok,
    unsigned short* __restrict__ ab,
    const float* __restrict__ upW, unsigned short* __restrict__ wtU) {
  __shared__ float4 ltq[TILE_B / 16];
  int b = blockIdx.x;
  if (b < G_GATH) gather_tile_body(x, tok, ab, b, (char*)ltq);
  else            cvt_tile_body(upW, wtU, b - G_GATH, NKT_UP, H_DIM, (char*)ltq);
}

// standalone cvt (fallback path for down-weights)
__global__ __launch_bounds__(512) void cvt_tile_w(
    const float* __restrict__ W, unsigned short* __restrict__ out,
    int NKT, int K) {
  __shared__ float4 ltq[TILE_B / 16];
  cvt_tile_body(W, out, blockIdx.x, NKT, K, (char*)ltq);
}

// ---------------- 8-phase 256^2 grouped-GEMM core (spread quarter-tile staging) ----------------
#define STAGE_FULL(KT, BS) do {                                                \
    const char* aT_ = aTile + (size_t)(KT) * TILE_B;                           \
    const char* bT_ = bTile + (size_t)(KT) * TILE_B;                           \
    _Pragma("unroll")                                                          \
    for (int l_ = 0; l_ < 4; ++l_) {                                           \
      int off_ = (l_ * 8 + wv) * 1024 + lane16;                                \
      gload16(aT_ + off_, smem + (BS) * 32768 + off_);                         \
      gload16(bT_ + off_, smem + 65536 + (BS) * 32768 + off_);                 \
    }                                                                          \
  } while (0)

#define STAGE_Q(KT, BS, Q) do {                                                \
    const char* aT_ = aTile + (size_t)(KT) * TILE_B;                           \
    const char* bT_ = bTile + (size_t)(KT) * TILE_B;                           \
    int off_ = ((Q) * 8 + wv) * 1024 + lane16;                                 \
    gload16(aT_ + off_, smem + (BS) * 32768 + off_);                           \
    gload16(bT_ + off_, smem + 65536 + (BS) * 32768 + off_);                   \
  } while (0)

#define PHASE(KS, FH, DO_STAGE, DO_VM) do {                                    \
    bf16x8 af[4];                                                              \
    const char* aB_ = smem + bufc * 32768 + ((KS) * 4 + hi) * 4096;            \
    _Pragma("unroll")                                                          \
    for (int f = 0; f < 4; ++f)                                                \
      af[f] = *(const bf16x8*)(aB_ + arow_b + ((FH) * 4 + f) * 256);           \
    if ((FH) == 0) {                                                           \
      const char* bB_ = smem + 65536 + bufc * 32768 + ((KS) * 4 + hi) * 4096;  \
      _Pragma("unroll")                                                        \
      for (int f = 0; f < 4; ++f)                                              \
        bfr[f] = *(const bf16x8*)(bB_ + brow_b + f * 256);                     \
    }                                                                          \
    DO_STAGE;                                                                  \
    DO_VM;                                                                     \
    __builtin_amdgcn_s_barrier();                                              \
    asm volatile("s_waitcnt lgkmcnt(0)" ::: "memory");                         \
    __builtin_amdgcn_s_setprio(1);                                             \
    _Pragma("unroll")                                                          \
    for (int fm = 0; fm < 4; ++fm)                                             \
      _Pragma("unroll")                                                        \
      for (int fn = 0; fn < 4; ++fn)                                           \
        acc[(FH) * 4 + fm][fn] = __builtin_amdgcn_mfma_f32_16x16x32_bf16(      \
            af[fm], bfr[fn], acc[(FH) * 4 + fm][fn], 0, 0, 0);                 \
    __builtin_amdgcn_s_setprio(0);                                             \
    __builtin_amdgcn_s_barrier();                                              \
  } while (0)

#define GEMM_PROLOGUE()                                                        \
  STAGE_FULL(0, 0);                                                            \
  asm volatile("s_waitcnt vmcnt(4)" ::: "memory");                             \
  __builtin_amdgcn_s_barrier();

#define GEMM_MAIN(NKT)                                                         \
  int bufc = 0;                                                                \
  for (int kt = 0; kt < (NKT); ++kt) {                                         \
    int ktn = (kt + 1 < (NKT)) ? kt + 1 : (NKT) - 1;  /* clamp: uniform counts */\
    int bn_ = bufc ^ 1;                                                        \
    PHASE(0, 0, STAGE_Q(ktn, bn_, 0), (void)0);                                \
    PHASE(0, 1, STAGE_Q(ktn, bn_, 1),                                          \
          asm volatile("s_waitcnt vmcnt(4)" ::: "memory"));                    \
    PHASE(1, 0, STAGE_Q(ktn, bn_, 2), (void)0);                                \
    PHASE(1, 1, STAGE_Q(ktn, bn_, 3),                                          \
          asm volatile("s_waitcnt vmcnt(4)" ::: "memory"));                    \
    bufc ^= 1;                                                                 \
  }

// ---------------- up-tile body: Hb[rt] tile = relu2(A @ up^T), tiled write ----------------
__device__ __forceinline__ void up_tile_body(
    int rt, int nt, int e,
    const unsigned short* __restrict__ Ab, const unsigned short* __restrict__ WtU,
    unsigned short* __restrict__ Hb, char* smem) {
  int tid = threadIdx.x;
  int wv = tid >> 6, lane = tid & 63;
  int lane16 = lane * 16;
  const char* aTile = (const char*)Ab + (size_t)rt * NKT_UP * TILE_B;
  const char* bTile = (const char*)WtU + (size_t)(e * NTN_UP + nt) * NKT_UP * TILE_B;
  int wm = wv >> 2, wn = wv & 3;
  int hi = lane >> 4;
  int arow_b = (wm * 128 + (lane & 15)) * 16;
  int brow_b = (wn * 64 + (lane & 15)) * 16;
  f32x4 acc[8][4] = {};
  bf16x8 bfr[4];
  GEMM_PROLOGUE();
  GEMM_MAIN(NKT_UP);
  unsigned short* baseT = Hb + ((size_t)rt * NKT_DN + nt * 4 + wn) * TILE_S
                             + ((lane & 15) >> 3) * 2048 + (lane & 7);
  #pragma unroll
  for (int fm = 0; fm < 8; ++fm) {
    #pragma unroll
    for (int j = 0; j < 4; ++j) {
      int r = wm * 128 + hi * 4 + fm * 16 + j;
      unsigned short* rb = baseT + r * 8;
      #pragma unroll
      for (int fn = 0; fn < 4; ++fn) {
        float v = acc[fm][fn][j];
        v = v > 0.f ? v * v : 0.f;
        rb[fn * 4096] = f2bf(v);
      }
    }
  }
}

// ---------------- down-tile body: Yb[pair] cols = Hb[rt] @ down^T ----------------
__device__ __forceinline__ void down_tile_body(
    int rt, int nt, int e,
    const unsigned short* __restrict__ Hb, const unsigned short* __restrict__ WtD,
    unsigned short* __restrict__ Yb, const int* __restrict__ tok, char* smem) {
  int tid = threadIdx.x;
  int wv = tid >> 6, lane = tid & 63;
  int lane16 = lane * 16;
  const char* aTile = (const char*)Hb + (size_t)rt * NKT_DN * TILE_B;
  const char* bTile = (const char*)WtD + (size_t)(e * NTN_DN + nt) * NKT_DN * TILE_B;
  int wm = wv >> 2, wn = wv & 3;
  int hi = lane >> 4;
  int arow_b = (wm * 128 + (lane & 15)) * 16;
  int brow_b = (wn * 64 + (lane & 15)) * 16;
  f32x4 acc[8][4] = {};
  bf16x8 bfr[4];
  GEMM_PROLOGUE();
  GEMM_MAIN(NKT_DN);
  int row0 = rt * BM2;
  int crow0 = row0 + wm * 128 + hi * 4;
  int ccol0 = nt * BN2 + wn * 64 + (lane & 15);
  #pragma unroll
  for (int fm = 0; fm < 8; ++fm) {
    #pragma unroll
    for (int j = 0; j < 4; ++j) {
      int p = crow0 + fm * 16 + j;
      int i = tok[p];
      if (i < 0) continue;
      unsigned short* dst = Yb + (size_t)i * H_DIM + ccol0;
      #pragma unroll
      for (int fn = 0; fn < 4; ++fn)
        dst[fn * 16] = f2bf(acc[fm][fn][j]);
    }
  }
}

// ---------------- FUSED GEMM1 + cvt_dn: blocks >= nGemm convert down-weights ----------------
__global__ __launch_bounds__(NTHR, 2) void gemm_up8f(
    const unsigned short* __restrict__ Ab, const unsigned short* __restrict__ WtU,
    unsigned short* __restrict__ Hb, const int* __restrict__ meta,
    const float* __restrict__ dnW, unsigned short* __restrict__ WtD,
    int nGemm) {
  extern __shared__ char smem[];
  if ((int)blockIdx.x >= nGemm) {
    cvt_tile_body(dnW, WtD, (int)blockIdx.x - nGemm, NKT_DN, I_DIM, smem);
    return;
  }
  const int* pstart = meta + 16;
  int rt, nt;
  rt_nt_decode(blockIdx.x, NTN_UP, rt, nt);
  if (rt * BM2 >= pstart[NE]) return;
  int e = expert_of(rt * BM2, pstart);
  up_tile_body(rt, nt, e, Ab, WtU, Hb, smem);
}

// ---------------- GEMM2: ybuf[pair] = h @ down_tiled^T ----------------
__global__ __launch_bounds__(NTHR, 2) void gemm_down8(
    const unsigned short* __restrict__ Hb, const unsigned short* __restrict__ Wt,
    unsigned short* __restrict__ Yb, const int* __restrict__ meta,
    const int* __restrict__ tok) {
  extern __shared__ char smem[];
  const int* pstart = meta + 16;
  int rt, nt;
  rt_nt_decode(blockIdx.x, NTN_DN, rt, nt);
  if (rt * BM2 >= pstart[NE]) return;
  int e = expert_of(rt * BM2, pstart);
  down_tile_body(rt, nt, e, Hb, Wt, Yb, tok, smem);
}

// ---------------- combine: out[t] = w0*y[2t] + w1*y[2t+1] (4 tokens/block) ----------------
__global__ __launch_bounds__(256) void combine(
    const unsigned short* __restrict__ Yb, const float* __restrict__ tkw,
    float* __restrict__ out) {
  int h0 = threadIdx.x * 8;
  #pragma unroll
  for (int tt = 0; tt < 4; ++tt) {
    int t = blockIdx.x * 4 + tt;
    float w0 = tkw[2 * t], w1 = tkw[2 * t + 1];
    bf16x8 ya = *(const bf16x8*)(Yb + (size_t)(2 * t) * H_DIM + h0);
    bf16x8 yb = *(const bf16x8*)(Yb + (size_t)(2 * t + 1) * H_DIM + h0);
    float* dst = out + (size_t)t * H_DIM + h0;
    float4 o0, o1;
    o0.x = w0 * b2f((unsigned short)ya[0]) + w1 * b2f((unsigned short)yb[0]);
    o0.y = w0 * b2f((unsigned short)ya[1]) + w1 * b2f((unsigned short)yb[1]);
    o0.z = w0 * b2f((unsigned short)ya[2]) + w1 * b2f((unsigned short)yb[2]);
    o0.w = w0 * b2f((unsigned short)ya[3]) + w1 * b2f((unsigned short)yb[3]);
    o1.x = w0 * b2f((unsigned short)ya[4]) + w1 * b2f((unsigned short)yb[4]);
    o1.y = w0 * b2f((unsigned short)ya[5]) + w1 * b2f((unsigned short)yb[5]);
    o1.z = w0 * b2f((unsigned short)ya[6]) + w1 * b2f((unsigned short)yb[6]);
    o1.w = w0 * b2f((unsigned short)ya[7]) + w1 * b2f((unsigned short)yb[7]);
    ((float4*)dst)[0] = o0;
    ((float4*)dst)[1] = o1;
  }
}

// ---------------- launch ----------------
extern "C" void kernel_launch(void* const* d_in, const int* in_sizes, int n_in,
                              void* d_out, int out_size, void* d_ws, size_t ws_size,
                              hipStream_t stream) {
  const float* x   = (const float*)d_in[0];
  const int*   tki = (const int*)d_in[1];
  const float* tkw = (const float*)d_in[2];
  const float* up  = (const float*)d_in[3];
  const float* dn  = (const float*)d_in[4];
  float* out = (float*)d_out;
  char* ws = (char*)d_ws;

  // Fused layout: AB | WtU | WtD | Hb | tok | meta   (~495 MB)
  // Serial layout: AB | Wt(shared) | Hb | tok | meta (~361 MB) — WtD == WtU.
  size_t need_fused = AB_BYTES + 2 * W_BYTES + HB_BYTES + TOK_BYTES + 4096;
  bool fused = ws_size >= need_fused;

  char* p = ws;
  unsigned short* ab  = (unsigned short*)p; p += AB_BYTES;
  unsigned short* wtU = (unsigned short*)p; p += W_BYTES;
  unsigned short* wtD = fused ? (unsigned short*)p : wtU;
  if (fused) p += W_BYTES;
  unsigned short* hb  = (unsigned short*)p; p += HB_BYTES;
  int* tok  = (int*)p; p += TOK_BYTES;
  int* meta = (int*)p;
  unsigned short* yb = ab;              // Yb overlaps dead Ab

  hipFuncSetAttribute((const void*)gemm_up8f,
                      hipFuncAttributeMaxDynamicSharedMemorySize, 131072);
  hipFuncSetAttribute((const void*)gemm_down8,
                      hipFuncAttributeMaxDynamicSharedMemorySize, 131072);

  route_all<<<1, 512, 0, stream>>>(tki, meta, tok);

  // fused independent producers: gather-A + cvt-up (one launch, one tail)
  gather_cvt_up<<<G_GATH + G_CVTU, 512, 0, stream>>>(x, tok, ab, up, wtU);

  if (fused) {
    // gemm_up blocks first (start immediately); cvt_dn blocks fill the tail.
    gemm_up8f<<<G_UP + G_CVTD, NTHR, 131072, stream>>>(ab, wtU, hb, meta,
                                                       dn, wtD, G_UP);
  } else {
    gemm_up8f<<<G_UP, NTHR, 131072, stream>>>(ab, wtU, hb, meta, dn, wtD, G_UP);
    cvt_tile_w<<<G_CVTD, 512, 0, stream>>>(dn, wtD, NKT_DN, I_DIM);
  }

  gemm_down8<<<G_DN, NTHR, 131072, stream>>>(hb, wtD, yb, meta, tok);

  combine<<<T_TOKENS / 4, 256, 0, stream>>>(yb, tkw, out);
}